// Round 3
// baseline (4811.643 us; speedup 1.0000x reference)
//
#include <hip/hip_runtime.h>
#include <hip/hip_fp16.h>

typedef _Float16 half8 __attribute__((ext_vector_type(8)));
typedef _Float16 half4v __attribute__((ext_vector_type(4)));
typedef float floatx4 __attribute__((ext_vector_type(4)));

constexpr int BN = 128;    // batch
constexpr int T  = 1024;   // time steps
constexpr int D  = 512;    // input dim
constexpr int H  = 512;    // hidden dim

// Workspace layout (bytes)
constexpr size_t OFF_WIHT = 0;                    // W_ih^T f16 = 512 KB
constexpr size_t OFF_WHHT = 524288;               // W_hh^T f16 = 512 KB
constexpr size_t OFF_XP   = 2097152;              // xp f16 [T][B][H] = 128 MB

__device__ __forceinline__ float fast_tanh(float x) {
    float e = __expf(2.0f * x);
    return 1.0f - 2.0f / (e + 1.0f);
}

// ---------------------------------------------------------------------------
// Prep: transpose 512x512 fp32 -> fp16 (row-major [n][k] = W[k][n])
// ---------------------------------------------------------------------------
__global__ __launch_bounds__(256) void prep_transpose(
    const float* __restrict__ Wih, const float* __restrict__ Whh,
    _Float16* __restrict__ WihT, _Float16* __restrict__ WhhT)
{
    __shared__ float tile[32][33];
    const float* src = (blockIdx.z == 0) ? Wih : Whh;
    _Float16* dst    = (blockIdx.z == 0) ? WihT : WhhT;
    const int tx = threadIdx.x & 31;
    const int ty = threadIdx.x >> 5;
    const int kbase = blockIdx.y * 32;
    const int nbase = blockIdx.x * 32;
    for (int r = 0; r < 4; ++r)
        tile[ty + r * 8][tx] = src[(size_t)(kbase + ty + r * 8) * 512 + nbase + tx];
    __syncthreads();
    for (int r = 0; r < 4; ++r)
        dst[(size_t)(nbase + ty + r * 8) * 512 + kbase + tx] =
            (_Float16)tile[tx][ty + r * 8];
}

// ---------------------------------------------------------------------------
// Phase 1: xp[t][b][n] = x[b][t][:] @ W_ih + bias   (fp16 out, bias folded)
// ---------------------------------------------------------------------------
__global__ __launch_bounds__(256) void xp_gemm(
    const float* __restrict__ x, const _Float16* __restrict__ WT,
    const float* __restrict__ bias, _Float16* __restrict__ xp)
{
    __shared__ _Float16 As[128][40];
    __shared__ _Float16 Bs[128][40];
    const int tid  = threadIdx.x;
    const int lane = tid & 63;
    const int w    = tid >> 6;
    const int wm   = w & 1, wn = w >> 1;
    const int l15  = lane & 15, q = lane >> 4;
    const size_t mbase = (size_t)blockIdx.y * 128;
    const int    nbase = blockIdx.x * 128;

    floatx4 acc[4][4];
    for (int i = 0; i < 4; ++i)
        for (int j = 0; j < 4; ++j)
            acc[i][j] = (floatx4){0.f, 0.f, 0.f, 0.f};

    for (int kt = 0; kt < 16; ++kt) {
        const int k0 = kt * 32;
        {
            const int k4 = (tid & 7) * 4;
            const int row0 = tid >> 3;
            for (int r = 0; r < 4; ++r) {
                const int row = row0 + r * 32;
                const float4 v = *(const float4*)&x[(mbase + row) * D + k0 + k4];
                half4v hv;
                hv[0] = (_Float16)v.x; hv[1] = (_Float16)v.y;
                hv[2] = (_Float16)v.z; hv[3] = (_Float16)v.w;
                *(half4v*)&As[row][k4] = hv;
            }
        }
        {
            const int k8 = (tid & 3) * 8;
            const int n0 = tid >> 2;
            for (int r = 0; r < 2; ++r) {
                const int n = n0 + r * 64;
                *(half8*)&Bs[n][k8] =
                    *(const half8*)&WT[(size_t)(nbase + n) * D + k0 + k8];
            }
        }
        __syncthreads();
        half8 a[4], b[4];
        for (int i = 0; i < 4; ++i)
            a[i] = *(const half8*)&As[wm * 64 + i * 16 + l15][q * 8];
        for (int j = 0; j < 4; ++j)
            b[j] = *(const half8*)&Bs[wn * 64 + j * 16 + l15][q * 8];
        for (int i = 0; i < 4; ++i)
            for (int j = 0; j < 4; ++j)
                acc[i][j] = __builtin_amdgcn_mfma_f32_16x16x32_f16(
                    a[i], b[j], acc[i][j], 0, 0, 0);
        __syncthreads();
    }
    float bc[4];
    for (int j = 0; j < 4; ++j)
        bc[j] = bias[nbase + wn * 64 + j * 16 + l15];
    for (int i = 0; i < 4; ++i)
        for (int r = 0; r < 4; ++r) {
            const size_t row = mbase + wm * 64 + i * 16 + q * 4 + r;
            const int b_row = (int)(row >> 10);      // T = 1024
            const int tt    = (int)(row & 1023);
            _Float16* dst = &xp[((size_t)tt * BN + b_row) * H];
            for (int j = 0; j < 4; ++j) {
                const int col = nbase + wn * 64 + j * 16 + l15;
                dst[col] = (_Float16)(acc[i][j][r] + bc[j]);
            }
        }
}

// ---------------------------------------------------------------------------
// Phase 2: sequential scan, one WG per 16-row batch group, zero inter-WG sync.
// 8 WGs x 512 threads (8 waves), __launch_bounds__(512,2) => 256-VGPR budget,
// 1 block/CU. Wave w owns hidden cols [w*64, w*64+64).
// K split (16 tiles of 32): c0..11 PINNED IN REGISTERS (192 VGPR),
// c12 resident in LDS, c13..15 streamed from L2 each step through ONE 16-reg
// buffer with fixed addresses, interleaved for latency:
//   [load c13] c0..c9 | use c13 [load c14] | c10, c12(LDS) | use c14
//   [load c15] | c11 | use c15
// h in LDS, MFMA-fragment-permuted (b128 reads / b64 writes, conflict-free).
// ---------------------------------------------------------------------------
__global__ __launch_bounds__(512, 2) void rnn_scan(
    const _Float16* __restrict__ xp, const _Float16* __restrict__ WT,
    float* __restrict__ out)
{
    __shared__ _Float16 hbuf[2][16 * 512];        // 32 KB, frag-permuted
    __shared__ _Float16 wlds[8 * 4 * 4 * 16 * 8]; // 32 KB, c=12 W tile

    const int g    = blockIdx.x;
    const int tid  = threadIdx.x;
    const int lane = tid & 63;
    const int w    = tid >> 6;           // wave 0..7
    const int l15  = lane & 15;
    const int q    = lane >> 4;

    // W row pointers for this wave's 4 m-tiles (fixed all kernel)
    const _Float16* wr0 = WT + (size_t)(w * 64 + 0 * 16 + l15) * H + q * 8;
    const _Float16* wr1 = WT + (size_t)(w * 64 + 1 * 16 + l15) * H + q * 8;
    const _Float16* wr2 = WT + (size_t)(w * 64 + 2 * 16 + l15) * H + q * 8;
    const _Float16* wr3 = WT + (size_t)(w * 64 + 3 * 16 + l15) * H + q * 8;

    // ---- pin k-tiles c=0..11 in registers: wf[c][i]
    half8 wf[12][4];
#pragma unroll
    for (int c = 0; c < 12; ++c) {
        wf[c][0] = *(const half8*)&wr0[c * 32];
        wf[c][1] = *(const half8*)&wr1[c * 32];
        wf[c][2] = *(const half8*)&wr2[c * 32];
        wf[c][3] = *(const half8*)&wr3[c * 32];
    }
    // ---- k-tile c=12 into LDS (per-wave slice, fragment order)
    *(half8*)&wlds[(((w * 4 + 0) * 4 + q) * 16 + l15) * 8] = *(const half8*)&wr0[12 * 32];
    *(half8*)&wlds[(((w * 4 + 1) * 4 + q) * 16 + l15) * 8] = *(const half8*)&wr1[12 * 32];
    *(half8*)&wlds[(((w * 4 + 2) * 4 + q) * 16 + l15) * 8] = *(const half8*)&wr2[12 * 32];
    *(half8*)&wlds[(((w * 4 + 3) * 4 + q) * 16 + l15) * 8] = *(const half8*)&wr3[12 * 32];

    // ---- t = 0: h1 = tanh(xp_0) (bias folded into xp), h0 = 0.
    {
        const _Float16* x0 = xp + ((size_t)0 * BN + g * 16 + l15) * H;
#pragma unroll
        for (int i = 0; i < 4; ++i) {
            const int hid = w * 64 + i * 16 + q * 4;
            half4v v = *(const half4v*)&x0[hid];
            half4v hn;
            for (int r = 0; r < 4; ++r)
                hn[r] = (_Float16)fast_tanh((float)v[r]);
            const int c = hid >> 5, qr = (hid >> 3) & 3, lo = hid & 7;
            *(half4v*)&hbuf[1][((c * 4 + qr) * 16 + l15) * 8 + lo] = hn;
        }
        __syncthreads();
    }

    // lane-fixed xp offset; only the t-uniform base advances
    const _Float16* xlane = xp + ((size_t)g * 16 + l15) * H + w * 64 + q * 4;

    for (int t = 1; t < T; ++t) {
        const _Float16* hb = hbuf[t & 1];

        // prefetch xp_t (independent of h)
        const _Float16* xt = xlane + (size_t)t * (BN * H);
        half4v xpv0 = *(const half4v*)&xt[0];
        half4v xpv1 = *(const half4v*)&xt[16];
        half4v xpv2 = *(const half4v*)&xt[32];
        half4v xpv3 = *(const half4v*)&xt[48];

        // stream buffer <- c13
        half8 s0 = *(const half8*)&wr0[13 * 32];
        half8 s1 = *(const half8*)&wr1[13 * 32];
        half8 s2 = *(const half8*)&wr2[13 * 32];
        half8 s3 = *(const half8*)&wr3[13 * 32];

        floatx4 acc0 = (floatx4){0.f, 0.f, 0.f, 0.f};
        floatx4 acc1 = (floatx4){0.f, 0.f, 0.f, 0.f};
        floatx4 acc2 = (floatx4){0.f, 0.f, 0.f, 0.f};
        floatx4 acc3 = (floatx4){0.f, 0.f, 0.f, 0.f};

        // reg tiles c0..c9
#pragma unroll
        for (int c = 0; c < 10; ++c) {
            half8 hf = *(const half8*)&hb[((c * 4 + q) * 16 + l15) * 8];
            acc0 = __builtin_amdgcn_mfma_f32_16x16x32_f16(wf[c][0], hf, acc0, 0, 0, 0);
            acc1 = __builtin_amdgcn_mfma_f32_16x16x32_f16(wf[c][1], hf, acc1, 0, 0, 0);
            acc2 = __builtin_amdgcn_mfma_f32_16x16x32_f16(wf[c][2], hf, acc2, 0, 0, 0);
            acc3 = __builtin_amdgcn_mfma_f32_16x16x32_f16(wf[c][3], hf, acc3, 0, 0, 0);
        }
        // consume stream c13, reload buffer <- c14
        {
            half8 hf = *(const half8*)&hb[((13 * 4 + q) * 16 + l15) * 8];
            acc0 = __builtin_amdgcn_mfma_f32_16x16x32_f16(s0, hf, acc0, 0, 0, 0);
            acc1 = __builtin_amdgcn_mfma_f32_16x16x32_f16(s1, hf, acc1, 0, 0, 0);
            acc2 = __builtin_amdgcn_mfma_f32_16x16x32_f16(s2, hf, acc2, 0, 0, 0);
            acc3 = __builtin_amdgcn_mfma_f32_16x16x32_f16(s3, hf, acc3, 0, 0, 0);
            s0 = *(const half8*)&wr0[14 * 32];
            s1 = *(const half8*)&wr1[14 * 32];
            s2 = *(const half8*)&wr2[14 * 32];
            s3 = *(const half8*)&wr3[14 * 32];
        }
        // reg tile c10
        {
            half8 hf = *(const half8*)&hb[((10 * 4 + q) * 16 + l15) * 8];
            acc0 = __builtin_amdgcn_mfma_f32_16x16x32_f16(wf[10][0], hf, acc0, 0, 0, 0);
            acc1 = __builtin_amdgcn_mfma_f32_16x16x32_f16(wf[10][1], hf, acc1, 0, 0, 0);
            acc2 = __builtin_amdgcn_mfma_f32_16x16x32_f16(wf[10][2], hf, acc2, 0, 0, 0);
            acc3 = __builtin_amdgcn_mfma_f32_16x16x32_f16(wf[10][3], hf, acc3, 0, 0, 0);
        }
        // LDS W tile c12
        {
            half8 hf = *(const half8*)&hb[((12 * 4 + q) * 16 + l15) * 8];
            half8 wl0 = *(const half8*)&wlds[(((w * 4 + 0) * 4 + q) * 16 + l15) * 8];
            half8 wl1 = *(const half8*)&wlds[(((w * 4 + 1) * 4 + q) * 16 + l15) * 8];
            half8 wl2 = *(const half8*)&wlds[(((w * 4 + 2) * 4 + q) * 16 + l15) * 8];
            half8 wl3 = *(const half8*)&wlds[(((w * 4 + 3) * 4 + q) * 16 + l15) * 8];
            acc0 = __builtin_amdgcn_mfma_f32_16x16x32_f16(wl0, hf, acc0, 0, 0, 0);
            acc1 = __builtin_amdgcn_mfma_f32_16x16x32_f16(wl1, hf, acc1, 0, 0, 0);
            acc2 = __builtin_amdgcn_mfma_f32_16x16x32_f16(wl2, hf, acc2, 0, 0, 0);
            acc3 = __builtin_amdgcn_mfma_f32_16x16x32_f16(wl3, hf, acc3, 0, 0, 0);
        }
        // consume stream c14, reload buffer <- c15
        {
            half8 hf = *(const half8*)&hb[((14 * 4 + q) * 16 + l15) * 8];
            acc0 = __builtin_amdgcn_mfma_f32_16x16x32_f16(s0, hf, acc0, 0, 0, 0);
            acc1 = __builtin_amdgcn_mfma_f32_16x16x32_f16(s1, hf, acc1, 0, 0, 0);
            acc2 = __builtin_amdgcn_mfma_f32_16x16x32_f16(s2, hf, acc2, 0, 0, 0);
            acc3 = __builtin_amdgcn_mfma_f32_16x16x32_f16(s3, hf, acc3, 0, 0, 0);
            s0 = *(const half8*)&wr0[15 * 32];
            s1 = *(const half8*)&wr1[15 * 32];
            s2 = *(const half8*)&wr2[15 * 32];
            s3 = *(const half8*)&wr3[15 * 32];
        }
        // reg tile c11
        {
            half8 hf = *(const half8*)&hb[((11 * 4 + q) * 16 + l15) * 8];
            acc0 = __builtin_amdgcn_mfma_f32_16x16x32_f16(wf[11][0], hf, acc0, 0, 0, 0);
            acc1 = __builtin_amdgcn_mfma_f32_16x16x32_f16(wf[11][1], hf, acc1, 0, 0, 0);
            acc2 = __builtin_amdgcn_mfma_f32_16x16x32_f16(wf[11][2], hf, acc2, 0, 0, 0);
            acc3 = __builtin_amdgcn_mfma_f32_16x16x32_f16(wf[11][3], hf, acc3, 0, 0, 0);
        }
        // consume stream c15
        {
            half8 hf = *(const half8*)&hb[((15 * 4 + q) * 16 + l15) * 8];
            acc0 = __builtin_amdgcn_mfma_f32_16x16x32_f16(s0, hf, acc0, 0, 0, 0);
            acc1 = __builtin_amdgcn_mfma_f32_16x16x32_f16(s1, hf, acc1, 0, 0, 0);
            acc2 = __builtin_amdgcn_mfma_f32_16x16x32_f16(s2, hf, acc2, 0, 0, 0);
            acc3 = __builtin_amdgcn_mfma_f32_16x16x32_f16(s3, hf, acc3, 0, 0, 0);
        }

        if (t < T - 1) {
            _Float16* ho = hbuf[(t + 1) & 1];
            const floatx4 av[4] = {acc0, acc1, acc2, acc3};
            const half4v xv[4] = {xpv0, xpv1, xpv2, xpv3};
#pragma unroll
            for (int i = 0; i < 4; ++i) {
                const int hid = w * 64 + i * 16 + q * 4;
                half4v hn;
                for (int r = 0; r < 4; ++r)
                    hn[r] = (_Float16)fast_tanh(av[i][r] + (float)xv[i][r]);
                const int c = hid >> 5, qr = (hid >> 3) & 3, lo = hid & 7;
                *(half4v*)&ho[((c * 4 + qr) * 16 + l15) * 8 + lo] = hn;
            }
            __syncthreads();
        } else {
            const floatx4 av[4] = {acc0, acc1, acc2, acc3};
            const half4v xv[4] = {xpv0, xpv1, xpv2, xpv3};
#pragma unroll
            for (int i = 0; i < 4; ++i) {
                const int hid = w * 64 + i * 16 + q * 4;
                float4 o;
                o.x = fast_tanh(av[i][0] + (float)xv[i][0]);
                o.y = fast_tanh(av[i][1] + (float)xv[i][1]);
                o.z = fast_tanh(av[i][2] + (float)xv[i][2]);
                o.w = fast_tanh(av[i][3] + (float)xv[i][3]);
                *(float4*)&out[(size_t)(g * 16 + l15) * H + hid] = o;
            }
        }
    }
}

// ---------------------------------------------------------------------------
extern "C" void kernel_launch(void* const* d_in, const int* in_sizes, int n_in,
                              void* d_out, int out_size, void* d_ws, size_t ws_size,
                              hipStream_t stream)
{
    const float* x   = (const float*)d_in[0];
    const float* Wih = (const float*)d_in[1];
    const float* Whh = (const float*)d_in[2];
    const float* b   = (const float*)d_in[3];
    float* out = (float*)d_out;

    char* ws = (char*)d_ws;
    _Float16* WihT = (_Float16*)(ws + OFF_WIHT);
    _Float16* WhhT = (_Float16*)(ws + OFF_WHHT);
    _Float16* xp   = (_Float16*)(ws + OFF_XP);

    prep_transpose<<<dim3(16, 16, 2), 256, 0, stream>>>(Wih, Whh, WihT, WhhT);
    xp_gemm<<<dim3(4, 1024), 256, 0, stream>>>(x, WihT, b, xp);
    rnn_scan<<<8, 512, 0, stream>>>(xp, WhhT, out);
}

// Round 4
// 4465.279 us; speedup vs baseline: 1.0776x; 1.0776x over previous
//
#include <hip/hip_runtime.h>
#include <hip/hip_fp16.h>

typedef _Float16 half8 __attribute__((ext_vector_type(8)));
typedef _Float16 half4v __attribute__((ext_vector_type(4)));
typedef float floatx4 __attribute__((ext_vector_type(4)));

constexpr int BN = 128;    // batch
constexpr int T  = 1024;   // time steps
constexpr int D  = 512;    // input dim
constexpr int H  = 512;    // hidden dim

// Workspace layout (bytes)
constexpr size_t OFF_WIHT = 0;                    // W_ih^T f16 = 512 KB
constexpr size_t OFF_WHHT = 524288;               // W_hh^T f16 = 512 KB
constexpr size_t OFF_XP   = 2097152;              // xp f16 [T][B][H] = 128 MB

__device__ __forceinline__ float fast_tanh(float x) {
    float e = __expf(2.0f * x);
    return 1.0f - 2.0f / (e + 1.0f);
}

// ---------------------------------------------------------------------------
// Prep: transpose 512x512 fp32 -> fp16 (row-major [n][k] = W[k][n])
// ---------------------------------------------------------------------------
__global__ __launch_bounds__(256) void prep_transpose(
    const float* __restrict__ Wih, const float* __restrict__ Whh,
    _Float16* __restrict__ WihT, _Float16* __restrict__ WhhT)
{
    __shared__ float tile[32][33];
    const float* src = (blockIdx.z == 0) ? Wih : Whh;
    _Float16* dst    = (blockIdx.z == 0) ? WihT : WhhT;
    const int tx = threadIdx.x & 31;
    const int ty = threadIdx.x >> 5;
    const int kbase = blockIdx.y * 32;
    const int nbase = blockIdx.x * 32;
    for (int r = 0; r < 4; ++r)
        tile[ty + r * 8][tx] = src[(size_t)(kbase + ty + r * 8) * 512 + nbase + tx];
    __syncthreads();
    for (int r = 0; r < 4; ++r)
        dst[(size_t)(nbase + ty + r * 8) * 512 + kbase + tx] =
            (_Float16)tile[tx][ty + r * 8];
}

// ---------------------------------------------------------------------------
// Phase 1: xp[t][b][n] = x[b][t][:] @ W_ih + bias   (fp16 out, bias folded)
// ---------------------------------------------------------------------------
__global__ __launch_bounds__(256) void xp_gemm(
    const float* __restrict__ x, const _Float16* __restrict__ WT,
    const float* __restrict__ bias, _Float16* __restrict__ xp)
{
    __shared__ _Float16 As[128][40];
    __shared__ _Float16 Bs[128][40];
    const int tid  = threadIdx.x;
    const int lane = tid & 63;
    const int w    = tid >> 6;
    const int wm   = w & 1, wn = w >> 1;
    const int l15  = lane & 15, q = lane >> 4;
    const size_t mbase = (size_t)blockIdx.y * 128;
    const int    nbase = blockIdx.x * 128;

    floatx4 acc[4][4];
    for (int i = 0; i < 4; ++i)
        for (int j = 0; j < 4; ++j)
            acc[i][j] = (floatx4){0.f, 0.f, 0.f, 0.f};

    for (int kt = 0; kt < 16; ++kt) {
        const int k0 = kt * 32;
        {
            const int k4 = (tid & 7) * 4;
            const int row0 = tid >> 3;
            for (int r = 0; r < 4; ++r) {
                const int row = row0 + r * 32;
                const float4 v = *(const float4*)&x[(mbase + row) * D + k0 + k4];
                half4v hv;
                hv[0] = (_Float16)v.x; hv[1] = (_Float16)v.y;
                hv[2] = (_Float16)v.z; hv[3] = (_Float16)v.w;
                *(half4v*)&As[row][k4] = hv;
            }
        }
        {
            const int k8 = (tid & 3) * 8;
            const int n0 = tid >> 2;
            for (int r = 0; r < 2; ++r) {
                const int n = n0 + r * 64;
                *(half8*)&Bs[n][k8] =
                    *(const half8*)&WT[(size_t)(nbase + n) * D + k0 + k8];
            }
        }
        __syncthreads();
        half8 a[4], b[4];
        for (int i = 0; i < 4; ++i)
            a[i] = *(const half8*)&As[wm * 64 + i * 16 + l15][q * 8];
        for (int j = 0; j < 4; ++j)
            b[j] = *(const half8*)&Bs[wn * 64 + j * 16 + l15][q * 8];
        for (int i = 0; i < 4; ++i)
            for (int j = 0; j < 4; ++j)
                acc[i][j] = __builtin_amdgcn_mfma_f32_16x16x32_f16(
                    a[i], b[j], acc[i][j], 0, 0, 0);
        __syncthreads();
    }
    float bc[4];
    for (int j = 0; j < 4; ++j)
        bc[j] = bias[nbase + wn * 64 + j * 16 + l15];
    for (int i = 0; i < 4; ++i)
        for (int r = 0; r < 4; ++r) {
            const size_t row = mbase + wm * 64 + i * 16 + q * 4 + r;
            const int b_row = (int)(row >> 10);      // T = 1024
            const int tt    = (int)(row & 1023);
            _Float16* dst = &xp[((size_t)tt * BN + b_row) * H];
            for (int j = 0; j < 4; ++j) {
                const int col = nbase + wn * 64 + j * 16 + l15;
                dst[col] = (_Float16)(acc[i][j][r] + bc[j]);
            }
        }
}

// ---------------------------------------------------------------------------
// Phase 2: sequential scan, one WG (8 waves) per 16-row batch group, zero
// inter-WG sync. W_hh^T (512 KB = the whole CU regfile) is partitioned so
// residency is GUARANTEED, not left to RA heuristics (R2/R3 failure: RA
// spilled the 192-reg wf array and refetched ~393 KB/step from L2):
//   c0..c7  : AGPRs, forced via empty asm "+a" (128 AGPRs; MFMA reads A
//             directly from AGPR on gfx950 — no move insts)
//   c8..c9  : arch VGPRs (32 regs; arch total ~100 < 128, no spill)
//   c10..c12: LDS (96 KB), fragment-ordered, conflict-free b128 reads
//   c13..c15: streamed from L2 each step via one rotating 16-reg buffer
// h in LDS double buffer (32 KB), MFMA-fragment-permuted layout.
// ---------------------------------------------------------------------------
__global__ __launch_bounds__(512, 2) void rnn_scan(
    const _Float16* __restrict__ xp, const _Float16* __restrict__ WT,
    float* __restrict__ out)
{
    __shared__ _Float16 hbuf[2][16 * 512];           // 32 KB
    __shared__ _Float16 wlds[3][8 * 4 * 4 * 16 * 8]; // 3 x 32 KB

    const int g    = blockIdx.x;
    const int tid  = threadIdx.x;
    const int lane = tid & 63;
    const int w    = tid >> 6;           // wave 0..7
    const int l15  = lane & 15;
    const int q    = lane >> 4;

    // W row pointers for this wave's 4 m-tiles (fixed all kernel)
    const _Float16* wr0 = WT + (size_t)(w * 64 + 0 * 16 + l15) * H + q * 8;
    const _Float16* wr1 = WT + (size_t)(w * 64 + 1 * 16 + l15) * H + q * 8;
    const _Float16* wr2 = WT + (size_t)(w * 64 + 2 * 16 + l15) * H + q * 8;
    const _Float16* wr3 = WT + (size_t)(w * 64 + 3 * 16 + l15) * H + q * 8;

    // ---- c0..c7 -> AGPRs
    half8 wa[8][4];
#pragma unroll
    for (int c = 0; c < 8; ++c) {
        wa[c][0] = *(const half8*)&wr0[c * 32];
        wa[c][1] = *(const half8*)&wr1[c * 32];
        wa[c][2] = *(const half8*)&wr2[c * 32];
        wa[c][3] = *(const half8*)&wr3[c * 32];
    }
#pragma unroll
    for (int c = 0; c < 8; ++c)
        asm volatile("" : "+a"(wa[c][0]), "+a"(wa[c][1]),
                          "+a"(wa[c][2]), "+a"(wa[c][3]));

    // ---- c8..c9 -> arch VGPRs
    half8 wv[2][4];
#pragma unroll
    for (int c = 0; c < 2; ++c) {
        wv[c][0] = *(const half8*)&wr0[(8 + c) * 32];
        wv[c][1] = *(const half8*)&wr1[(8 + c) * 32];
        wv[c][2] = *(const half8*)&wr2[(8 + c) * 32];
        wv[c][3] = *(const half8*)&wr3[(8 + c) * 32];
    }

    // ---- c10..c12 -> LDS (per-wave slice, fragment order)
#pragma unroll
    for (int c = 0; c < 3; ++c) {
        *(half8*)&wlds[c][(((w * 4 + 0) * 4 + q) * 16 + l15) * 8] = *(const half8*)&wr0[(10 + c) * 32];
        *(half8*)&wlds[c][(((w * 4 + 1) * 4 + q) * 16 + l15) * 8] = *(const half8*)&wr1[(10 + c) * 32];
        *(half8*)&wlds[c][(((w * 4 + 2) * 4 + q) * 16 + l15) * 8] = *(const half8*)&wr2[(10 + c) * 32];
        *(half8*)&wlds[c][(((w * 4 + 3) * 4 + q) * 16 + l15) * 8] = *(const half8*)&wr3[(10 + c) * 32];
    }

    // ---- t = 0: h1 = tanh(xp_0) (bias folded into xp), h0 = 0.
    {
        const _Float16* x0 = xp + ((size_t)0 * BN + g * 16 + l15) * H;
#pragma unroll
        for (int i = 0; i < 4; ++i) {
            const int hid = w * 64 + i * 16 + q * 4;
            half4v v = *(const half4v*)&x0[hid];
            half4v hn;
            for (int r = 0; r < 4; ++r)
                hn[r] = (_Float16)fast_tanh((float)v[r]);
            const int c = hid >> 5, qr = (hid >> 3) & 3, lo = hid & 7;
            *(half4v*)&hbuf[1][((c * 4 + qr) * 16 + l15) * 8 + lo] = hn;
        }
        __syncthreads();
    }

    // lane-fixed xp offset; only the t-uniform base advances
    const _Float16* xlane = xp + ((size_t)g * 16 + l15) * H + w * 64 + q * 4;

    for (int t = 1; t < T; ++t) {
        const _Float16* hb = hbuf[t & 1];

        // prefetch xp_t (independent of h)
        const _Float16* xt = xlane + (size_t)t * (BN * H);
        half4v xpv0 = *(const half4v*)&xt[0];
        half4v xpv1 = *(const half4v*)&xt[16];
        half4v xpv2 = *(const half4v*)&xt[32];
        half4v xpv3 = *(const half4v*)&xt[48];

        // stream buffer <- c13
        half8 s0 = *(const half8*)&wr0[13 * 32];
        half8 s1 = *(const half8*)&wr1[13 * 32];
        half8 s2 = *(const half8*)&wr2[13 * 32];
        half8 s3 = *(const half8*)&wr3[13 * 32];

        floatx4 acc0 = (floatx4){0.f, 0.f, 0.f, 0.f};
        floatx4 acc1 = (floatx4){0.f, 0.f, 0.f, 0.f};
        floatx4 acc2 = (floatx4){0.f, 0.f, 0.f, 0.f};
        floatx4 acc3 = (floatx4){0.f, 0.f, 0.f, 0.f};

        // AGPR tiles c0..c7
#pragma unroll
        for (int c = 0; c < 8; ++c) {
            half8 hf = *(const half8*)&hb[((c * 4 + q) * 16 + l15) * 8];
            acc0 = __builtin_amdgcn_mfma_f32_16x16x32_f16(wa[c][0], hf, acc0, 0, 0, 0);
            acc1 = __builtin_amdgcn_mfma_f32_16x16x32_f16(wa[c][1], hf, acc1, 0, 0, 0);
            acc2 = __builtin_amdgcn_mfma_f32_16x16x32_f16(wa[c][2], hf, acc2, 0, 0, 0);
            acc3 = __builtin_amdgcn_mfma_f32_16x16x32_f16(wa[c][3], hf, acc3, 0, 0, 0);
        }
        // consume stream c13, reload <- c14
        {
            half8 hf = *(const half8*)&hb[((13 * 4 + q) * 16 + l15) * 8];
            acc0 = __builtin_amdgcn_mfma_f32_16x16x32_f16(s0, hf, acc0, 0, 0, 0);
            acc1 = __builtin_amdgcn_mfma_f32_16x16x32_f16(s1, hf, acc1, 0, 0, 0);
            acc2 = __builtin_amdgcn_mfma_f32_16x16x32_f16(s2, hf, acc2, 0, 0, 0);
            acc3 = __builtin_amdgcn_mfma_f32_16x16x32_f16(s3, hf, acc3, 0, 0, 0);
            s0 = *(const half8*)&wr0[14 * 32];
            s1 = *(const half8*)&wr1[14 * 32];
            s2 = *(const half8*)&wr2[14 * 32];
            s3 = *(const half8*)&wr3[14 * 32];
        }
        // VGPR tiles c8..c9
#pragma unroll
        for (int c = 0; c < 2; ++c) {
            half8 hf = *(const half8*)&hb[(((8 + c) * 4 + q) * 16 + l15) * 8];
            acc0 = __builtin_amdgcn_mfma_f32_16x16x32_f16(wv[c][0], hf, acc0, 0, 0, 0);
            acc1 = __builtin_amdgcn_mfma_f32_16x16x32_f16(wv[c][1], hf, acc1, 0, 0, 0);
            acc2 = __builtin_amdgcn_mfma_f32_16x16x32_f16(wv[c][2], hf, acc2, 0, 0, 0);
            acc3 = __builtin_amdgcn_mfma_f32_16x16x32_f16(wv[c][3], hf, acc3, 0, 0, 0);
        }
        // LDS W tile c10
        {
            half8 hf = *(const half8*)&hb[((10 * 4 + q) * 16 + l15) * 8];
            half8 wl0 = *(const half8*)&wlds[0][(((w * 4 + 0) * 4 + q) * 16 + l15) * 8];
            half8 wl1 = *(const half8*)&wlds[0][(((w * 4 + 1) * 4 + q) * 16 + l15) * 8];
            half8 wl2 = *(const half8*)&wlds[0][(((w * 4 + 2) * 4 + q) * 16 + l15) * 8];
            half8 wl3 = *(const half8*)&wlds[0][(((w * 4 + 3) * 4 + q) * 16 + l15) * 8];
            acc0 = __builtin_amdgcn_mfma_f32_16x16x32_f16(wl0, hf, acc0, 0, 0, 0);
            acc1 = __builtin_amdgcn_mfma_f32_16x16x32_f16(wl1, hf, acc1, 0, 0, 0);
            acc2 = __builtin_amdgcn_mfma_f32_16x16x32_f16(wl2, hf, acc2, 0, 0, 0);
            acc3 = __builtin_amdgcn_mfma_f32_16x16x32_f16(wl3, hf, acc3, 0, 0, 0);
        }
        // consume stream c14, reload <- c15
        {
            half8 hf = *(const half8*)&hb[((14 * 4 + q) * 16 + l15) * 8];
            acc0 = __builtin_amdgcn_mfma_f32_16x16x32_f16(s0, hf, acc0, 0, 0, 0);
            acc1 = __builtin_amdgcn_mfma_f32_16x16x32_f16(s1, hf, acc1, 0, 0, 0);
            acc2 = __builtin_amdgcn_mfma_f32_16x16x32_f16(s2, hf, acc2, 0, 0, 0);
            acc3 = __builtin_amdgcn_mfma_f32_16x16x32_f16(s3, hf, acc3, 0, 0, 0);
            s0 = *(const half8*)&wr0[15 * 32];
            s1 = *(const half8*)&wr1[15 * 32];
            s2 = *(const half8*)&wr2[15 * 32];
            s3 = *(const half8*)&wr3[15 * 32];
        }
        // LDS W tiles c11, c12
#pragma unroll
        for (int c = 1; c < 3; ++c) {
            half8 hf = *(const half8*)&hb[(((10 + c) * 4 + q) * 16 + l15) * 8];
            half8 wl0 = *(const half8*)&wlds[c][(((w * 4 + 0) * 4 + q) * 16 + l15) * 8];
            half8 wl1 = *(const half8*)&wlds[c][(((w * 4 + 1) * 4 + q) * 16 + l15) * 8];
            half8 wl2 = *(const half8*)&wlds[c][(((w * 4 + 2) * 4 + q) * 16 + l15) * 8];
            half8 wl3 = *(const half8*)&wlds[c][(((w * 4 + 3) * 4 + q) * 16 + l15) * 8];
            acc0 = __builtin_amdgcn_mfma_f32_16x16x32_f16(wl0, hf, acc0, 0, 0, 0);
            acc1 = __builtin_amdgcn_mfma_f32_16x16x32_f16(wl1, hf, acc1, 0, 0, 0);
            acc2 = __builtin_amdgcn_mfma_f32_16x16x32_f16(wl2, hf, acc2, 0, 0, 0);
            acc3 = __builtin_amdgcn_mfma_f32_16x16x32_f16(wl3, hf, acc3, 0, 0, 0);
        }
        // consume stream c15
        {
            half8 hf = *(const half8*)&hb[((15 * 4 + q) * 16 + l15) * 8];
            acc0 = __builtin_amdgcn_mfma_f32_16x16x32_f16(s0, hf, acc0, 0, 0, 0);
            acc1 = __builtin_amdgcn_mfma_f32_16x16x32_f16(s1, hf, acc1, 0, 0, 0);
            acc2 = __builtin_amdgcn_mfma_f32_16x16x32_f16(s2, hf, acc2, 0, 0, 0);
            acc3 = __builtin_amdgcn_mfma_f32_16x16x32_f16(s3, hf, acc3, 0, 0, 0);
        }

        if (t < T - 1) {
            _Float16* ho = hbuf[(t + 1) & 1];
            const floatx4 av[4] = {acc0, acc1, acc2, acc3};
            const half4v xv[4] = {xpv0, xpv1, xpv2, xpv3};
#pragma unroll
            for (int i = 0; i < 4; ++i) {
                const int hid = w * 64 + i * 16 + q * 4;
                half4v hn;
                for (int r = 0; r < 4; ++r)
                    hn[r] = (_Float16)fast_tanh(av[i][r] + (float)xv[i][r]);
                const int c = hid >> 5, qr = (hid >> 3) & 3, lo = hid & 7;
                *(half4v*)&ho[((c * 4 + qr) * 16 + l15) * 8 + lo] = hn;
            }
            __syncthreads();
        } else {
            const floatx4 av[4] = {acc0, acc1, acc2, acc3};
            const half4v xv[4] = {xpv0, xpv1, xpv2, xpv3};
#pragma unroll
            for (int i = 0; i < 4; ++i) {
                const int hid = w * 64 + i * 16 + q * 4;
                float4 o;
                o.x = fast_tanh(av[i][0] + (float)xv[i][0]);
                o.y = fast_tanh(av[i][1] + (float)xv[i][1]);
                o.z = fast_tanh(av[i][2] + (float)xv[i][2]);
                o.w = fast_tanh(av[i][3] + (float)xv[i][3]);
                *(float4*)&out[(size_t)(g * 16 + l15) * H + hid] = o;
            }
        }
    }
}

// ---------------------------------------------------------------------------
extern "C" void kernel_launch(void* const* d_in, const int* in_sizes, int n_in,
                              void* d_out, int out_size, void* d_ws, size_t ws_size,
                              hipStream_t stream)
{
    const float* x   = (const float*)d_in[0];
    const float* Wih = (const float*)d_in[1];
    const float* Whh = (const float*)d_in[2];
    const float* b   = (const float*)d_in[3];
    float* out = (float*)d_out;

    char* ws = (char*)d_ws;
    _Float16* WihT = (_Float16*)(ws + OFF_WIHT);
    _Float16* WhhT = (_Float16*)(ws + OFF_WHHT);
    _Float16* xp   = (_Float16*)(ws + OFF_XP);

    prep_transpose<<<dim3(16, 16, 2), 256, 0, stream>>>(Wih, Whh, WihT, WhhT);
    xp_gemm<<<dim3(4, 1024), 256, 0, stream>>>(x, WihT, b, xp);
    rnn_scan<<<8, 512, 0, stream>>>(xp, WhhT, out);
}